// Round 3
// baseline (2208.158 us; speedup 1.0000x reference)
//
#include <hip/hip_runtime.h>
#include <hip/hip_bf16.h>

using bf16 = __hip_bfloat16;

#define N_  2
#define C_  512
#define T_  96
#define H_  14
#define W_  14
#define HW_ 196
#define RC_ 32
#define B_  (N_*T_)   // 192

// fp32 vec arena offsets
#define VQB   0
#define VKB   512
#define VVB   1024
#define VCB   1536
#define VQRY  2048
#define VSAB  2560   // 96 (3x32)
#define VW2   2688   // 6
#define VW4   2696   // 3
#define VWTS  2700   // 3
#define VECS_TOTAL 2720

__device__ __forceinline__ float b2f(bf16 v){ return __bfloat162float(v); }
__device__ __forceinline__ float sigm(float x){ return 1.f/(1.f+__expf(-x)); }

// dual-dtype load: inputs may be fp32 or bf16 (flag decided by probe kernel)
__device__ __forceinline__ float ldd(const void* p, size_t i, bool f32){
    if (f32) return ((const float*)p)[i];
    else     return b2f(((const bf16*)p)[i]);
}

// ---------- probe: decide whether inputs are fp32 or bf16 ----------
// bf16 N(0,1): exponent field within ~[110,130]; fp32 halves: low halves have
// uniform-random exponent fields -> ~50/128 "wild".
__global__ void probe_kernel(const void* __restrict__ x, int* __restrict__ flag){
    if (blockIdx.x==0 && threadIdx.x==0){
        const unsigned short* h = (const unsigned short*)x;
        int wild = 0;
        for (int i=0;i<128;i++){
            int e = (h[i] >> 7) & 0xFF;
            if (e < 100 || e > 150) wild++;
        }
        flag[0] = (wild > 16) ? 1 : 0;   // 1 => fp32 inputs
    }
}

// ---------- prep: down_conv2_w -> fp32 transposed  w2t[in][out] ----------
__global__ void prep_w2t_kernel(const void* __restrict__ dcw2, float* __restrict__ w2t,
                                const int* __restrict__ flag){
    bool f32 = flag[0]!=0;
    int i = blockIdx.x*256 + threadIdx.x;
    if (i < C_*C_){
        int in = i / C_, out = i % C_;
        w2t[i] = ldd(dcw2, (size_t)out*C_ + in, f32);   // w2t[in*C+out] = W[out][in]
    }
}

// ---------- prep: everything small -> fp32 arenas ----------
#define PM_TOTAL (16384+16384+7776+512*5+96+6+3+3)
__global__ void prep_misc_kernel(const void* dcw, const void* cbw,
                                 const void* sa1w, const void* sa2w, const void* sa3w,
                                 const void* q_b, const void* k_b, const void* v_b,
                                 const void* c_b, const void* query,
                                 const void* sa1b, const void* sa2b, const void* sa3b,
                                 const void* w2, const void* w4, const void* wts,
                                 float* __restrict__ dwt, float* __restrict__ cbwf,
                                 float* __restrict__ saw, float* __restrict__ vecs,
                                 const int* __restrict__ flag){
    bool f32 = flag[0]!=0;
    int i = blockIdx.x*256 + threadIdx.x;
    if (i >= PM_TOTAL) return;
    if (i < 16384){ int c=i>>5, r=i&31; dwt[i] = ldd(dcw, (size_t)r*C_+c, f32); return; }
    i -= 16384;
    if (i < 16384){ cbwf[i] = ldd(cbw, i, f32); return; }
    i -= 16384;
    if (i < 7776){
        const void* s = (i<2592)? sa1w : ((i<5184)? sa2w : sa3w);
        int j = (i<2592)? i : ((i<5184)? i-2592 : i-5184);
        saw[i] = ldd(s, j, f32); return;
    }
    i -= 7776;
    if (i < 512){ vecs[VQB +i] = ldd(q_b,  i, f32); return; } i -= 512;
    if (i < 512){ vecs[VKB +i] = ldd(k_b,  i, f32); return; } i -= 512;
    if (i < 512){ vecs[VVB +i] = ldd(v_b,  i, f32); return; } i -= 512;
    if (i < 512){ vecs[VCB +i] = ldd(c_b,  i, f32); return; } i -= 512;
    if (i < 512){ vecs[VQRY+i] = ldd(query,i, f32); return; } i -= 512;
    if (i < 96){
        const void* s = (i<32)? sa1b : ((i<64)? sa2b : sa3b);
        vecs[VSAB+i] = ldd(s, i&31, f32); return;
    }
    i -= 96;
    if (i < 6){ vecs[VW2+i] = ldd(w2, i, f32); return; } i -= 6;
    if (i < 3){ vecs[VW4+i] = ldd(w4, i, f32); return; } i -= 3;
    vecs[VWTS+i] = ldd(wts, i, f32);
}

// ---------- K1: fold query/q/k projections into one C-vector ----------
__global__ void qproj_kernel(const void* __restrict__ q_w, const void* __restrict__ k_w,
                             const float* __restrict__ vecs, float* __restrict__ qk_out,
                             const int* __restrict__ flag){
    bool f32 = flag[0]!=0;
    __shared__ float qp_s[C_];
    int c = threadIdx.x;                       // 512 threads
    float acc = 0.f;
    for (int i=0;i<C_;i++) acc += vecs[VQRY+i] * ldd(q_w, (size_t)c*C_+i, f32);
    qp_s[c] = (acc + vecs[VQB+c]) * 0.044194173824159216f;   // 512^-0.5
    __syncthreads();
    float a2 = 0.f;
    for (int i=0;i<C_;i++) a2 += qp_s[i] * ldd(k_w, (size_t)i*C_ + c, f32);
    qk_out[c] = a2;
    if (c==0){
        float d=0.f;
        for (int i=0;i<C_;i++) d += qp_s[i]*vecs[VKB+i];
        qk_out[C_] = d;
    }
}

// ---------- K2: attention softmax over 196 positions + pooled x ----------
__global__ void attn_pool_kernel(const void* __restrict__ x, const float* __restrict__ qk,
                                 float* __restrict__ pooled, const int* __restrict__ flag){
    bool f32 = flag[0]!=0;
    int b = blockIdx.x, n = b/T_, t = b%T_;
    __shared__ float qk_s[C_];
    __shared__ float sm[HW_];
    __shared__ float red[2];
    int tid = threadIdx.x;                     // 256 threads
    for (int i=tid;i<C_;i+=256) qk_s[i] = qk[i];
    __syncthreads();
    if (tid < HW_){
        float acc = qk[C_];
        size_t base = ((size_t)n*C_*T_ + t)*HW_ + tid;
        for (int c=0;c<C_;c++) acc += qk_s[c]*ldd(x, base + (size_t)c*T_*HW_, f32);
        sm[tid] = acc;
    }
    __syncthreads();
    if (tid==0){ float m=-1e30f; for(int l=0;l<HW_;l++) m=fmaxf(m,sm[l]); red[0]=m; }
    __syncthreads();
    if (tid < HW_) sm[tid] = __expf(sm[tid]-red[0]);
    __syncthreads();
    if (tid==0){ float s=0.f; for(int l=0;l<HW_;l++) s+=sm[l]; red[1]=1.f/s; }
    __syncthreads();
    if (tid < HW_) sm[tid] *= red[1];
    __syncthreads();
    for (int c=tid;c<C_;c+=256){
        size_t base = (((size_t)n*C_+c)*T_ + t)*HW_;
        float acc=0.f;
        for (int l=0;l<HW_;l++) acc += sm[l]*ldd(x, base+l, f32);
        pooled[(size_t)b*C_ + c] = acc;
    }
}

// ---------- K3: v/c projections of the pooled vector ----------
__global__ void att_proj_kernel(const float* __restrict__ pooled,
                                const void* __restrict__ v_w, const void* __restrict__ c_w,
                                const float* __restrict__ vecs, float* __restrict__ x_att,
                                const int* __restrict__ flag){
    bool f32 = flag[0]!=0;
    int b = blockIdx.x, c = threadIdx.x;       // 512 threads
    __shared__ float p_s[C_];
    __shared__ float pre_s[C_];
    p_s[c] = pooled[(size_t)b*C_ + c];
    __syncthreads();
    float acc = vecs[VVB+c];
    for (int i=0;i<C_;i++) acc += p_s[i]*ldd(v_w, (size_t)c*C_+i, f32);
    pre_s[c] = acc;
    __syncthreads();
    float a2 = vecs[VCB+c];
    for (int i=0;i<C_;i++) a2 += pre_s[i]*ldd(c_w, (size_t)c*C_+i, f32);
    x_att[(size_t)b*C_ + c] = a2;
}

// ---------- K4: xq = w4[0]*mean + w4[1]*max + w4[2]*x_att ----------
__global__ void xq_kernel(const void* __restrict__ x, const float* __restrict__ x_att,
                          const float* __restrict__ vecs, float* __restrict__ xq,
                          const int* __restrict__ flag){
    bool f32 = flag[0]!=0;
    int b = blockIdx.x, n = b/T_, t = b%T_;
    float w40=vecs[VW4+0], w41=vecs[VW4+1], w42=vecs[VW4+2];
    for (int c=threadIdx.x;c<C_;c+=256){
        size_t base = (((size_t)n*C_+c)*T_ + t)*HW_;
        float s=0.f, m=-1e30f;
        for (int l=0;l<HW_;l++){ float v=ldd(x, base+l, f32); s+=v; m=fmaxf(m,v); }
        xq[(size_t)b*C_+c] = s*(1.f/HW_)*w40 + m*w41 + x_att[(size_t)b*C_+c]*w42;
    }
}

// ---------- K5: fused rank-factorized correlation ----------
// yq = W2^T xq ; aff[j,l] = <yq, x[:,tj,l]> ; g = w2j*(sigm(w2j*aff)-0.5)
// z[e] = sum_{j,l} g[j,l]*x[e,tj,l] ; feat = W2 z        (exact reordering)
__global__ void __launch_bounds__(256) corr_fused_kernel(const void* __restrict__ x,
        const void* __restrict__ dcw2, const float* __restrict__ w2t,
        const float* __restrict__ xq, const float* __restrict__ vecs,
        float* __restrict__ feat, const int* __restrict__ flag){
    bool f32 = flag[0]!=0;
    int b = blockIdx.x, n = b/T_, t = b%T_;
    __shared__ float xq_s[C_];
    __shared__ float yq_s[C_];
    __shared__ float z_s[C_];
    __shared__ float g_s[6*HW_];
    int tid = threadIdx.x;                     // 256
    for (int i=tid;i<C_;i+=256) xq_s[i] = xq[(size_t)b*C_+i];
    __syncthreads();
    for (int e=tid;e<C_;e+=256){
        float acc=0.f;
        for (int c=0;c<C_;c++) acc += xq_s[c]*ldd(dcw2, (size_t)c*C_+e, f32);
        yq_s[e]=acc;
    }
    __syncthreads();
    const int offs[6] = {-3,-2,-1,1,2,3};
    for (int i=tid;i<6*HW_;i+=256){
        int j=i/HW_, l=i-j*HW_;
        int tj = t + offs[j];
        float g = 0.f;
        if (tj>=0 && tj<T_){
            float w2j = vecs[VW2+j];
            size_t base = ((size_t)n*C_*T_ + tj)*HW_ + l;
            float acc=0.f;
            for (int e=0;e<C_;e++) acc += yq_s[e]*ldd(x, base + (size_t)e*T_*HW_, f32);
            g = w2j*(sigm(w2j*acc)-0.5f);
        }
        g_s[i]=g;
    }
    __syncthreads();
    for (int e=tid;e<C_;e+=256){
        size_t rowbase = ((size_t)n*C_+e)*T_*HW_;
        float acc=0.f;
        #pragma unroll
        for (int j=0;j<6;j++){
            int tj = t + offs[j];
            if (tj<0 || tj>=T_) continue;
            size_t base = rowbase + (size_t)tj*HW_;
            const float* gp = &g_s[j*HW_];
            for (int l=0;l<HW_;l++) acc += gp[l]*ldd(x, base+l, f32);
        }
        z_s[e]=acc;
    }
    __syncthreads();
    for (int c=tid;c<C_;c+=256){
        float acc=0.f;
        for (int e=0;e<C_;e++) acc += w2t[(size_t)e*C_+c]*z_s[e];
        feat[(size_t)b*C_+c]=acc;
    }
}

// ---------- K6: x_down = down_conv_w @ x (bf16 out) ----------
__global__ void __launch_bounds__(256) xdown_kernel(const void* __restrict__ x,
                                                    const float* __restrict__ dwt,
                                                    bf16* __restrict__ xd,
                                                    const int* __restrict__ flag){
    bool f32 = flag[0]!=0;
    int b = blockIdx.x, n = b/T_, t = b%T_;
    int hw = threadIdx.x;
    int hwc = hw < HW_ ? hw : HW_-1;
    float acc[RC_];
    #pragma unroll
    for (int r=0;r<RC_;r++) acc[r]=0.f;
    size_t xbase = ((size_t)n*C_*T_ + t)*HW_ + hwc;
    for (int c=0;c<C_;c++){
        float xv = ldd(x, xbase + (size_t)c*T_*HW_, f32);
        const float* wr = dwt + c*RC_;         // wave-uniform
        #pragma unroll
        for (int r=0;r<RC_;r++) acc[r] += wr[r]*xv;
    }
    if (hw < HW_){
        #pragma unroll
        for (int r=0;r<RC_;r++)
            xd[(((size_t)n*RC_ + r)*T_ + t)*HW_ + hw] = __float2bfloat16(acc[r]);
    }
}

// ---------- K7: 3-branch dilated depthwise conv, fused weighted sum ----------
__global__ void dwconv_kernel(const bf16* __restrict__ xd, const float* __restrict__ saw,
                              const float* __restrict__ vecs, bf16* __restrict__ aggs){
    int nr = blockIdx.x;            // n*RC_+r
    int r  = nr % RC_;
    int t0 = blockIdx.y*24;
    __shared__ float tile[32*HW_];  // frames [t0-4, t0+28), zero-padded
    __shared__ float wsm[3][81];
    __shared__ float wbr[3];
    __shared__ float cbias;
    int tid = threadIdx.x;          // 256
    if (tid < 81){
        wsm[0][tid]=saw[       r*81+tid];
        wsm[1][tid]=saw[2592 + r*81+tid];
        wsm[2][tid]=saw[5184 + r*81+tid];
    }
    if (tid==0){
        float w0=vecs[VWTS+0], w1=vecs[VWTS+1], w2v=vecs[VWTS+2];
        wbr[0]=w0; wbr[1]=w1; wbr[2]=w2v;
        cbias = w0*vecs[VSAB+r] + w1*vecs[VSAB+32+r] + w2v*vecs[VSAB+64+r];
    }
    const bf16* base = xd + (size_t)nr*T_*HW_;
    for (int i=tid;i<32*HW_;i+=256){
        int tt=i/HW_, hh=i%HW_;
        int tg = t0 - 4 + tt;
        tile[i] = (tg>=0 && tg<T_) ? b2f(base[(size_t)tg*HW_+hh]) : 0.f;
    }
    __syncthreads();
    for (int i=tid;i<24*HW_;i+=256){
        int tl=i/HW_, hw=i%HW_;
        int h=hw/W_, w=hw%W_;
        float acc = cbias;
        #pragma unroll
        for (int br=0;br<3;br++){
            int d = br+1;
            float s = 0.f;
            for (int kt=0;kt<9;kt++){
                const float* trow = &tile[(tl+kt)*HW_];
                #pragma unroll
                for (int kh=0;kh<3;kh++){
                    int hh = h + (kh-1)*d;
                    if (hh<0||hh>=H_) continue;
                    #pragma unroll
                    for (int kw=0;kw<3;kw++){
                        int ww = w + (kw-1)*d;
                        if (ww<0||ww>=W_) continue;
                        s += wsm[br][kt*9+kh*3+kw]*trow[hh*W_+ww];
                    }
                }
            }
            acc += wbr[br]*s;
        }
        aggs[(size_t)nr*T_*HW_ + (size_t)(t0+tl)*HW_ + hw] = __float2bfloat16(acc);
    }
}

// ---------- K8: conv_back + sigmoid gate * feat -> FP32 out ----------
__global__ void __launch_bounds__(256) final_kernel(const bf16* __restrict__ aggs,
                                                    const float* __restrict__ cbwf,
                                                    const float* __restrict__ feat,
                                                    float* __restrict__ out){
    int b = blockIdx.x, n = b/T_, t = b%T_;
    int c0 = blockIdx.y*128;
    __shared__ float s_agg[RC_*HW_];
    int tid = threadIdx.x;
    for (int i=tid;i<RC_*HW_;i+=256){
        int r=i/HW_, hw=i%HW_;
        s_agg[i] = b2f(aggs[(((size_t)n*RC_+r)*T_ + t)*HW_ + hw]);
    }
    __syncthreads();
    int hw = tid;
    if (hw < HW_){
        for (int ci=0;ci<128;ci++){
            int c = c0+ci;
            const float* wr = cbwf + c*RC_;    // wave-uniform
            float a = 0.f;
            #pragma unroll
            for (int r=0;r<RC_;r++) a += wr[r]*s_agg[r*HW_+hw];
            float f = feat[(size_t)b*C_+c];
            out[(((size_t)n*C_+c)*T_ + t)*HW_ + hw] = f*(sigm(a)-0.5f);
        }
    }
}

extern "C" void kernel_launch(void* const* d_in, const int* in_sizes, int n_in,
                              void* d_out, int out_size, void* d_ws, size_t ws_size,
                              hipStream_t stream){
    const void* x      = d_in[0];
    const void* dcw2   = d_in[1];   // down_conv2_w (C,C)
    const void* dcw    = d_in[2];   // down_conv_w  (rc,C)
    const void* cbw    = d_in[3];   // conv_back_w  (C,rc)
    const void* w2     = d_in[4];   // weights2 (6)
    const void* w4     = d_in[5];   // weights4 (3)
    const void* wts    = d_in[6];   // weights  (3)
    const void* query  = d_in[7];
    const void* q_w    = d_in[8];
    const void* q_b    = d_in[9];
    const void* k_w    = d_in[10];
    const void* k_b    = d_in[11];
    const void* v_w    = d_in[12];
    const void* v_b    = d_in[13];
    const void* c_w    = d_in[14];
    const void* c_b    = d_in[15];
    const void* sa1w   = d_in[16];
    const void* sa1b   = d_in[17];
    const void* sa2w   = d_in[18];
    const void* sa2b   = d_in[19];
    const void* sa3w   = d_in[20];
    const void* sa3b   = d_in[21];
    float* out = (float*)d_out;     // reference output dtype is float32

    // workspace layout — total ~7.6 MB
    float* ws    = (float*)d_ws;
    int*   flag  = (int*)ws;               // 16 reserved
    float* qk    = ws + 16;                // 1024
    float* pooled= qk + 1024;              // 98304
    float* x_att = pooled + 98304;         // 98304
    float* xq    = x_att + 98304;          // 98304
    float* feat  = xq + 98304;             // 98304
    float* w2t   = feat + 98304;           // 262144
    float* dwt   = w2t + 262144;           // 16384
    float* cbwf  = dwt + 16384;            // 16384
    float* saw   = cbwf + 16384;           // 7936 (uses 7776)
    float* vecs  = saw + 7936;             // 2720
    bf16*  xd    = (bf16*)(vecs + VECS_TOTAL);   // 1204224 bf16
    bf16*  aggs  = xd + 1204224;                 // 1204224 bf16

    probe_kernel<<<1, 64, 0, stream>>>(x, flag);
    prep_w2t_kernel<<<(C_*C_+255)/256, 256, 0, stream>>>(dcw2, w2t, flag);
    prep_misc_kernel<<<(PM_TOTAL+255)/256, 256, 0, stream>>>(
        dcw, cbw, sa1w, sa2w, sa3w, q_b, k_b, v_b, c_b, query,
        sa1b, sa2b, sa3b, w2, w4, wts, dwt, cbwf, saw, vecs, flag);

    // attention-pool branch
    qproj_kernel<<<1, C_, 0, stream>>>(q_w, k_w, vecs, qk, flag);
    attn_pool_kernel<<<B_, 256, 0, stream>>>(x, qk, pooled, flag);
    att_proj_kernel<<<B_, C_, 0, stream>>>(pooled, v_w, c_w, vecs, x_att, flag);
    xq_kernel<<<B_, 256, 0, stream>>>(x, x_att, vecs, xq, flag);

    // rank-factorized correlation (no x2 tensor!)
    corr_fused_kernel<<<B_, 256, 0, stream>>>(x, dcw2, w2t, xq, vecs, feat, flag);

    // dilated depthwise branch
    xdown_kernel<<<B_, 256, 0, stream>>>(x, dwt, xd, flag);
    dwconv_kernel<<<dim3(N_*RC_, 4), 256, 0, stream>>>(xd, saw, vecs, aggs);
    final_kernel<<<dim3(B_, 4), 256, 0, stream>>>(aggs, cbwf, feat, out);
}

// Round 4
// 1421.323 us; speedup vs baseline: 1.5536x; 1.5536x over previous
//
#include <hip/hip_runtime.h>
#include <hip/hip_bf16.h>

using bf16 = __hip_bfloat16;
typedef __attribute__((ext_vector_type(4))) unsigned short ushort4v;

#define N_  2
#define C_  512
#define T_  96
#define H_  14
#define W_  14
#define HW_ 196
#define RC_ 32
#define B_  (N_*T_)    // 192
#define SC_ (T_*HW_)   // 18816 elems per channel
#define SN_ (C_*SC_)   // elems per batch
#define XTOT (N_*C_*T_*HW_)  // 19267584

// fp32 vec arena offsets
#define VQB   0
#define VKB   512
#define VVB   1024
#define VCB   1536
#define VQRY  2048
#define VSAB  2560   // 96 (3x32)
#define VW2   2688   // 6
#define VW4   2696   // 3
#define VWTS  2700   // 3
#define VECS_TOTAL 2720

__device__ __forceinline__ float b2f(bf16 v){ return __bfloat162float(v); }
__device__ __forceinline__ float u2f(unsigned short u){ return __uint_as_float(((unsigned)u)<<16); }
__device__ __forceinline__ float sigm(float x){ return 1.f/(1.f+__expf(-x)); }

__device__ __forceinline__ float ldd(const void* p, size_t i, bool f32){
    if (f32) return ((const float*)p)[i];
    else     return b2f(((const bf16*)p)[i]);
}

// ---------- probe: fp32 vs bf16 inputs ----------
__global__ void probe_kernel(const void* __restrict__ x, int* __restrict__ flag){
    if (blockIdx.x==0 && threadIdx.x==0){
        const unsigned short* h = (const unsigned short*)x;
        int wild = 0;
        for (int i=0;i<128;i++){
            int e = (h[i] >> 7) & 0xFF;
            if (e < 100 || e > 150) wild++;
        }
        flag[0] = (wild > 16) ? 1 : 0;   // 1 => fp32 inputs
    }
}

// ---------- prep: down_conv2_w -> fp32 transposed  w2t[e][o] = W[o][e] ----------
__global__ void prep_w2t_kernel(const void* __restrict__ dcw2, float* __restrict__ w2t,
                                const int* __restrict__ flag){
    bool f32 = flag[0]!=0;
    int i = blockIdx.x*256 + threadIdx.x;
    if (i < C_*C_){
        int in = i / C_, out = i % C_;
        w2t[i] = ldd(dcw2, (size_t)out*C_ + in, f32);
    }
}

// ---------- prep: small weights -> fp32 arenas (+ v_w/c_w transposes) ----------
#define PM_OLD (16384+16384+7776+512*5+96+6+3+3)
#define PM_TOTAL (PM_OLD + 262144 + 262144)
__global__ void prep_misc_kernel(const void* dcw, const void* cbw,
                                 const void* sa1w, const void* sa2w, const void* sa3w,
                                 const void* q_b, const void* k_b, const void* v_b,
                                 const void* c_b, const void* query,
                                 const void* sa1b, const void* sa2b, const void* sa3b,
                                 const void* w2, const void* w4, const void* wts,
                                 const void* v_w, const void* c_w,
                                 float* __restrict__ dwt, float* __restrict__ cbwf,
                                 float* __restrict__ saw, float* __restrict__ vecs,
                                 float* __restrict__ vwt, float* __restrict__ cwt,
                                 const int* __restrict__ flag){
    bool f32 = flag[0]!=0;
    int i = blockIdx.x*256 + threadIdx.x;
    if (i >= PM_TOTAL) return;
    if (i < 16384){ int c=i>>5, r=i&31; dwt[i] = ldd(dcw, (size_t)r*C_+c, f32); return; }
    i -= 16384;
    if (i < 16384){ cbwf[i] = ldd(cbw, i, f32); return; }
    i -= 16384;
    if (i < 7776){
        const void* s = (i<2592)? sa1w : ((i<5184)? sa2w : sa3w);
        int j = (i<2592)? i : ((i<5184)? i-2592 : i-5184);
        saw[i] = ldd(s, j, f32); return;
    }
    i -= 7776;
    if (i < 512){ vecs[VQB +i] = ldd(q_b,  i, f32); return; } i -= 512;
    if (i < 512){ vecs[VKB +i] = ldd(k_b,  i, f32); return; } i -= 512;
    if (i < 512){ vecs[VVB +i] = ldd(v_b,  i, f32); return; } i -= 512;
    if (i < 512){ vecs[VCB +i] = ldd(c_b,  i, f32); return; } i -= 512;
    if (i < 512){ vecs[VQRY+i] = ldd(query,i, f32); return; } i -= 512;
    if (i < 96){
        const void* s = (i<32)? sa1b : ((i<64)? sa2b : sa3b);
        vecs[VSAB+i] = ldd(s, i&31, f32); return;
    }
    i -= 96;
    if (i < 6){ vecs[VW2+i] = ldd(w2, i, f32); return; } i -= 6;
    if (i < 3){ vecs[VW4+i] = ldd(w4, i, f32); return; } i -= 3;
    if (i < 3){ vecs[VWTS+i] = ldd(wts, i, f32); return; } i -= 3;
    if (i < 262144){ int r=i/C_, c=i%C_; vwt[i] = ldd(v_w, (size_t)c*C_+r, f32); return; }
    i -= 262144;
    { int r=i/C_, c=i%C_; cwt[i] = ldd(c_w, (size_t)c*C_+r, f32); }
}

// ---------- T1: x -> bf16 copy (staged in first half of d_out) ----------
__global__ void cvt_x_kernel(const void* __restrict__ x, bf16* __restrict__ xb,
                             const int* __restrict__ flag){
    bool f32 = flag[0]!=0;
    int i = blockIdx.x*256 + threadIdx.x;
    if (i < XTOT) xb[i] = __float2bfloat16(ldd(x, i, f32));
}

// ---------- K1: fold query/q/k projections into one C-vector ----------
__global__ void qproj_kernel(const void* __restrict__ q_w, const void* __restrict__ k_w,
                             const float* __restrict__ vecs, float* __restrict__ qk_out,
                             const int* __restrict__ flag){
    bool f32 = flag[0]!=0;
    __shared__ float qp_s[C_];
    int c = threadIdx.x;                       // 512 threads
    float acc = 0.f;
    for (int i=0;i<C_;i++) acc += vecs[VQRY+i] * ldd(q_w, (size_t)c*C_+i, f32);
    qp_s[c] = (acc + vecs[VQB+c]) * 0.044194173824159216f;   // 512^-0.5
    __syncthreads();
    float a2 = 0.f;
    for (int i=0;i<C_;i++) a2 += qp_s[i] * ldd(k_w, (size_t)i*C_ + c, f32);
    qk_out[c] = a2;
    if (c==0){
        float d=0.f;
        for (int i=0;i<C_;i++) d += qp_s[i]*vecs[VKB+i];
        qk_out[C_] = d;
    }
}

// ---------- F1: attn logits + softmax + pooled / (mean,max part of xq) ----------
__global__ void __launch_bounds__(256) f1_kernel(const bf16* __restrict__ xb,
        const float* __restrict__ qk, const float* __restrict__ vecs,
        float* __restrict__ pooled, float* __restrict__ mm){
    int b = blockIdx.x, n = b/T_, t = b%T_;
    __shared__ float qk_s[C_];
    __shared__ float sm[HW_];
    __shared__ float red[2];
    int tid = threadIdx.x;
    for (int i=tid;i<C_;i+=256) qk_s[i] = qk[i];
    __syncthreads();
    if (tid < HW_){
        float acc = qk[C_];
        const bf16* p = xb + (size_t)n*SN_ + (size_t)t*HW_ + tid;
        for (int c=0;c<C_;c++) acc += qk_s[c]*b2f(p[(size_t)c*SC_]);
        sm[tid] = acc;
    }
    __syncthreads();
    if (tid==0){ float m=-1e30f; for(int l=0;l<HW_;l++) m=fmaxf(m,sm[l]); red[0]=m; }
    __syncthreads();
    if (tid < HW_) sm[tid] = __expf(sm[tid]-red[0]);
    __syncthreads();
    if (tid==0){ float s=0.f; for(int l=0;l<HW_;l++) s+=sm[l]; red[1]=1.f/s; }
    __syncthreads();
    if (tid < HW_) sm[tid] *= red[1];
    __syncthreads();
    float w40=vecs[VW4+0], w41=vecs[VW4+1];
    for (int c=tid;c<C_;c+=256){
        const bf16* base = xb + (size_t)n*SN_ + (size_t)c*SC_ + (size_t)t*HW_;
        float s=0.f, m=-1e30f, pl=0.f;
        for (int l4=0;l4<HW_;l4+=4){
            ushort4v u = *(const ushort4v*)(base + l4);
            #pragma unroll
            for (int k=0;k<4;k++){
                float v = u2f(u[k]);
                s += v; m = fmaxf(m,v); pl += sm[l4+k]*v;
            }
        }
        pooled[(size_t)b*C_+c] = pl;
        mm[(size_t)b*C_+c] = s*(1.f/HW_)*w40 + m*w41;
    }
}

// ---------- proj: v-proj -> c-proj -> xq -> yq (all coalesced) ----------
__global__ void __launch_bounds__(512) proj_kernel(const float* __restrict__ pooled,
        const float* __restrict__ mm, const float* __restrict__ vwt,
        const float* __restrict__ cwt, const void* __restrict__ dcw2,
        const float* __restrict__ vecs, float* __restrict__ xq,
        float* __restrict__ yq, const int* __restrict__ flag){
    bool f32 = flag[0]!=0;
    int b = blockIdx.x, c = threadIdx.x;       // 512 threads
    __shared__ float p_s[C_];
    __shared__ float pre_s[C_];
    __shared__ float xq_s[C_];
    p_s[c] = pooled[(size_t)b*C_ + c];
    __syncthreads();
    float pre = vecs[VVB+c];
    for (int i=0;i<C_;i++) pre += p_s[i]*vwt[(size_t)i*C_+c];
    pre_s[c] = pre;
    __syncthreads();
    float att = vecs[VCB+c];
    for (int i=0;i<C_;i++) att += pre_s[i]*cwt[(size_t)i*C_+c];
    float xqv = mm[(size_t)b*C_+c] + vecs[VW4+2]*att;
    xq[(size_t)b*C_+c] = xqv;
    xq_s[c] = xqv;
    __syncthreads();
    float yqv = 0.f;
    for (int i=0;i<C_;i++) yqv += xq_s[i]*ldd(dcw2, (size_t)i*C_+c, f32);
    yq[(size_t)b*C_+c] = yqv;
}

// ---------- corr2: gates + z + feat (rank-factorized correlation) ----------
__global__ void __launch_bounds__(256) corr2_kernel(const bf16* __restrict__ xb,
        const float* __restrict__ yq, const float* __restrict__ w2t,
        const float* __restrict__ vecs, float* __restrict__ feat){
    int b = blockIdx.x, n = b/T_, t = b%T_;
    int tid = threadIdx.x;
    __shared__ float yq_s[C_];
    __shared__ float g_s[6*HW_];
    __shared__ float z_s[C_];
    for (int i=tid;i<C_;i+=256) yq_s[i] = yq[(size_t)b*C_+i];
    __syncthreads();
    const int offs[6] = {-3,-2,-1,1,2,3};
    // ---- gate stage: thread = l ----
    if (tid < HW_){
        float accj[6] = {0.f,0.f,0.f,0.f,0.f,0.f};
        const bf16* pj[6];
        bool val[6];
        #pragma unroll
        for (int j=0;j<6;j++){
            int tj = t + offs[j];
            val[j] = (tj>=0 && tj<T_);
            pj[j] = xb + (size_t)n*SN_ + (size_t)(val[j]?tj:0)*HW_ + tid;
        }
        for (int e=0;e<C_;e++){
            size_t eo = (size_t)e*SC_;
            float yv = yq_s[e];
            #pragma unroll
            for (int j=0;j<6;j++) accj[j] += yv*b2f(pj[j][eo]);
        }
        #pragma unroll
        for (int j=0;j<6;j++){
            float w2j = vecs[VW2+j];
            g_s[j*HW_+tid] = val[j] ? w2j*(sigm(w2j*accj[j])-0.5f) : 0.f;
        }
    }
    __syncthreads();
    // ---- z stage: thread = e (2 chunks) ----
    {
        float acc0=0.f, acc1=0.f;
        const bf16* b0 = xb + (size_t)n*SN_ + (size_t)tid*SC_;
        const bf16* b1 = b0 + (size_t)256*SC_;
        #pragma unroll
        for (int j=0;j<6;j++){
            int tj = t + offs[j];
            if (tj<0 || tj>=T_) continue;
            const bf16* r0 = b0 + (size_t)tj*HW_;
            const bf16* r1 = b1 + (size_t)tj*HW_;
            const float* gp = &g_s[j*HW_];
            for (int l4=0;l4<HW_;l4+=4){
                ushort4v u0 = *(const ushort4v*)(r0+l4);
                ushort4v u1 = *(const ushort4v*)(r1+l4);
                #pragma unroll
                for (int k=0;k<4;k++){
                    float g = gp[l4+k];
                    acc0 += g*u2f(u0[k]);
                    acc1 += g*u2f(u1[k]);
                }
            }
        }
        z_s[tid]     = acc0;
        z_s[tid+256] = acc1;
    }
    __syncthreads();
    // ---- feat stage: thread = c (2 chunks), coalesced w2t ----
    for (int c=tid;c<C_;c+=256){
        float acc=0.f;
        for (int e=0;e<C_;e++) acc += w2t[(size_t)e*C_+c]*z_s[e];
        feat[(size_t)b*C_+c]=acc;
    }
}

// ---------- xdown: x_down = down_conv_w @ x (bf16 out) ----------
__global__ void __launch_bounds__(256) xdown_kernel(const bf16* __restrict__ xb,
                                                    const float* __restrict__ dwt,
                                                    bf16* __restrict__ xd){
    int b = blockIdx.x, n = b/T_, t = b%T_;
    int hw = threadIdx.x;
    int hwc = hw < HW_ ? hw : HW_-1;
    float acc[RC_];
    #pragma unroll
    for (int r=0;r<RC_;r++) acc[r]=0.f;
    const bf16* xp = xb + (size_t)n*SN_ + (size_t)t*HW_ + hwc;
    for (int c=0;c<C_;c++){
        float xv = b2f(xp[(size_t)c*SC_]);
        const float* wr = dwt + c*RC_;         // wave-uniform
        #pragma unroll
        for (int r=0;r<RC_;r++) acc[r] += wr[r]*xv;
    }
    if (hw < HW_){
        #pragma unroll
        for (int r=0;r<RC_;r++)
            xd[(((size_t)n*RC_ + r)*T_ + t)*HW_ + hw] = __float2bfloat16(acc[r]);
    }
}

// ---------- dwconv: 3-branch dilated depthwise conv, fused weighted sum ----------
__global__ void dwconv_kernel(const bf16* __restrict__ xd, const float* __restrict__ saw,
                              const float* __restrict__ vecs, float* __restrict__ aggs){
    int nr = blockIdx.x;            // n*RC_+r
    int r  = nr % RC_;
    int t0 = blockIdx.y*24;
    __shared__ float tile[32*HW_];  // frames [t0-4, t0+28), zero-padded
    __shared__ float wsm[3][81];
    __shared__ float wbr[3];
    __shared__ float cbias;
    int tid = threadIdx.x;          // 256
    if (tid < 81){
        wsm[0][tid]=saw[       r*81+tid];
        wsm[1][tid]=saw[2592 + r*81+tid];
        wsm[2][tid]=saw[5184 + r*81+tid];
    }
    if (tid==0){
        float w0=vecs[VWTS+0], w1=vecs[VWTS+1], w2v=vecs[VWTS+2];
        wbr[0]=w0; wbr[1]=w1; wbr[2]=w2v;
        cbias = w0*vecs[VSAB+r] + w1*vecs[VSAB+32+r] + w2v*vecs[VSAB+64+r];
    }
    const bf16* base = xd + (size_t)nr*T_*HW_;
    for (int i=tid;i<32*HW_;i+=256){
        int tt=i/HW_, hh=i%HW_;
        int tg = t0 - 4 + tt;
        tile[i] = (tg>=0 && tg<T_) ? b2f(base[(size_t)tg*HW_+hh]) : 0.f;
    }
    __syncthreads();
    for (int i=tid;i<24*HW_;i+=256){
        int tl=i/HW_, hw=i%HW_;
        int h=hw/W_, w=hw%W_;
        float acc = cbias;
        #pragma unroll
        for (int br=0;br<3;br++){
            int d = br+1;
            float s = 0.f;
            for (int kt=0;kt<9;kt++){
                const float* trow = &tile[(tl+kt)*HW_];
                #pragma unroll
                for (int kh=0;kh<3;kh++){
                    int hh = h + (kh-1)*d;
                    if (hh<0||hh>=H_) continue;
                    #pragma unroll
                    for (int kw=0;kw<3;kw++){
                        int ww = w + (kw-1)*d;
                        if (ww<0||ww>=W_) continue;
                        s += wsm[br][kt*9+kh*3+kw]*trow[hh*W_+ww];
                    }
                }
            }
            acc += wbr[br]*s;
        }
        aggs[(size_t)nr*T_*HW_ + (size_t)(t0+tl)*HW_ + hw] = acc;
    }
}

// ---------- final: conv_back (reg-resident agg) + gate * feat -> fp32 out ----------
__global__ void __launch_bounds__(256) final_kernel(const float* __restrict__ aggs,
                                                    const float* __restrict__ cbwf,
                                                    const float* __restrict__ feat,
                                                    float* __restrict__ out){
    int b = blockIdx.x, n = b/T_, t = b%T_;
    int c0 = blockIdx.y*128;
    int hw = threadIdx.x;
    if (hw >= HW_) return;
    float ra[RC_];
    #pragma unroll
    for (int r=0;r<RC_;r++)
        ra[r] = aggs[(((size_t)n*RC_+r)*T_ + t)*HW_ + hw];
    const float* fb = feat + (size_t)b*C_;
    for (int ci=0;ci<128;ci++){
        int c = c0+ci;
        const float* wr = cbwf + c*RC_;    // wave-uniform
        float a = 0.f;
        #pragma unroll
        for (int r=0;r<RC_;r++) a += wr[r]*ra[r];
        out[(((size_t)n*C_+c)*T_ + t)*HW_ + hw] = fb[c]*(sigm(a)-0.5f);
    }
}

extern "C" void kernel_launch(void* const* d_in, const int* in_sizes, int n_in,
                              void* d_out, int out_size, void* d_ws, size_t ws_size,
                              hipStream_t stream){
    const void* x      = d_in[0];
    const void* dcw2   = d_in[1];
    const void* dcw    = d_in[2];
    const void* cbw    = d_in[3];
    const void* w2     = d_in[4];
    const void* w4     = d_in[5];
    const void* wts    = d_in[6];
    const void* query  = d_in[7];
    const void* q_w    = d_in[8];
    const void* q_b    = d_in[9];
    const void* k_w    = d_in[10];
    const void* k_b    = d_in[11];
    const void* v_w    = d_in[12];
    const void* v_b    = d_in[13];
    const void* c_w    = d_in[14];
    const void* c_b    = d_in[15];
    const void* sa1w   = d_in[16];
    const void* sa1b   = d_in[17];
    const void* sa2w   = d_in[18];
    const void* sa2b   = d_in[19];
    const void* sa3w   = d_in[20];
    const void* sa3b   = d_in[21];
    float* out = (float*)d_out;

    // workspace layout — ~12.5 MB
    float* ws    = (float*)d_ws;
    int*   flag  = (int*)ws;               // 16
    float* qk    = ws + 16;                // 1024
    float* pooled= qk + 1024;              // 98304
    float* mm    = pooled + 98304;         // 98304
    float* xq    = mm + 98304;             // 98304
    float* yq    = xq + 98304;             // 98304
    float* feat  = yq + 98304;             // 98304
    float* w2t   = feat + 98304;           // 262144
    float* vwt   = w2t + 262144;           // 262144
    float* cwt   = vwt + 262144;           // 262144
    float* dwt   = cwt + 262144;           // 16384
    float* cbwf  = dwt + 16384;            // 16384
    float* saw   = cbwf + 16384;           // 7936 (uses 7776)
    float* vecs  = saw + 7936;             // 2720
    float* aggs  = vecs + VECS_TOTAL;      // 1204224 fp32
    bf16*  xd    = (bf16*)(aggs + 1204224);// 1204224 bf16
    // xb staged in the FIRST HALF of d_out (38.5 MB of 77 MB); fully consumed
    // by f1/corr2/xdown before final_kernel overwrites all of d_out.
    bf16*  xb    = (bf16*)d_out;

    probe_kernel<<<1, 64, 0, stream>>>(x, flag);
    prep_w2t_kernel<<<(C_*C_+255)/256, 256, 0, stream>>>(dcw2, w2t, flag);
    prep_misc_kernel<<<(PM_TOTAL+255)/256, 256, 0, stream>>>(
        dcw, cbw, sa1w, sa2w, sa3w, q_b, k_b, v_b, c_b, query,
        sa1b, sa2b, sa3b, w2, w4, wts, v_w, c_w,
        dwt, cbwf, saw, vecs, vwt, cwt, flag);
    cvt_x_kernel<<<(XTOT+255)/256, 256, 0, stream>>>(x, xb, flag);

    qproj_kernel<<<1, C_, 0, stream>>>(q_w, k_w, vecs, qk, flag);
    f1_kernel<<<B_, 256, 0, stream>>>(xb, qk, vecs, pooled, mm);
    proj_kernel<<<B_, C_, 0, stream>>>(pooled, mm, vwt, cwt, dcw2, vecs, xq, yq, flag);
    corr2_kernel<<<B_, 256, 0, stream>>>(xb, yq, w2t, vecs, feat);

    xdown_kernel<<<B_, 256, 0, stream>>>(xb, dwt, xd);
    dwconv_kernel<<<dim3(N_*RC_, 4), 256, 0, stream>>>(xd, saw, vecs, aggs);
    final_kernel<<<dim3(B_, 4), 256, 0, stream>>>(aggs, cbwf, feat, out);
}

// Round 5
// 954.896 us; speedup vs baseline: 2.3125x; 1.4885x over previous
//
#include <hip/hip_runtime.h>
#include <hip/hip_bf16.h>

using bf16 = __hip_bfloat16;
typedef __attribute__((ext_vector_type(4))) unsigned short ushort4v;

#define N_  2
#define C_  512
#define T_  96
#define H_  14
#define W_  14
#define HW_ 196
#define RC_ 32
#define B_  (N_*T_)    // 192
#define SC_ (T_*HW_)   // 18816 elems per channel
#define SN_ (C_*SC_)   // elems per batch
#define XTOT (N_*C_*T_*HW_)  // 19267584

// fp32 vec arena offsets
#define VQB   0
#define VKB   512
#define VVB   1024
#define VCB   1536
#define VQRY  2048
#define VSAB  2560   // 96 (3x32)
#define VW2   2688   // 6
#define VW4   2696   // 3
#define VWTS  2700   // 3
#define VECS_TOTAL 2720

__device__ __forceinline__ float b2f(bf16 v){ return __bfloat162float(v); }
__device__ __forceinline__ float u2f(unsigned short u){ return __uint_as_float(((unsigned)u)<<16); }
__device__ __forceinline__ float sigm(float x){ return 1.f/(1.f+__expf(-x)); }
__device__ __forceinline__ unsigned short f2bu(float f){
    bf16 b = __float2bfloat16(f);
    return *(unsigned short*)&b;
}

__device__ __forceinline__ float ldd(const void* p, size_t i, bool f32){
    if (f32) return ((const float*)p)[i];
    else     return b2f(((const bf16*)p)[i]);
}

// ---------- probe: fp32 vs bf16 inputs ----------
__global__ void probe_kernel(const void* __restrict__ x, int* __restrict__ flag){
    if (blockIdx.x==0 && threadIdx.x==0){
        const unsigned short* h = (const unsigned short*)x;
        int wild = 0;
        for (int i=0;i<128;i++){
            int e = (h[i] >> 7) & 0xFF;
            if (e < 100 || e > 150) wild++;
        }
        flag[0] = (wild > 16) ? 1 : 0;   // 1 => fp32 inputs
    }
}

// ---------- prep: down_conv2_w -> fp32 transposed  w2t[e][o] = W[o][e] ----------
__global__ void prep_w2t_kernel(const void* __restrict__ dcw2, float* __restrict__ w2t,
                                const int* __restrict__ flag){
    bool f32 = flag[0]!=0;
    int i = blockIdx.x*256 + threadIdx.x;
    if (i < C_*C_){
        int in = i / C_, out = i % C_;
        w2t[i] = ldd(dcw2, (size_t)out*C_ + in, f32);
    }
}

// ---------- prep: small weights -> fp32 arenas (+ v_w/c_w transposes) ----------
#define PM_OLD (16384+16384+7776+512*5+96+6+3+3)
#define PM_TOTAL (PM_OLD + 262144 + 262144)
__global__ void prep_misc_kernel(const void* dcw, const void* cbw,
                                 const void* sa1w, const void* sa2w, const void* sa3w,
                                 const void* q_b, const void* k_b, const void* v_b,
                                 const void* c_b, const void* query,
                                 const void* sa1b, const void* sa2b, const void* sa3b,
                                 const void* w2, const void* w4, const void* wts,
                                 const void* v_w, const void* c_w,
                                 float* __restrict__ dwt, float* __restrict__ cbwf,
                                 float* __restrict__ saw, float* __restrict__ vecs,
                                 float* __restrict__ vwt, float* __restrict__ cwt,
                                 const int* __restrict__ flag){
    bool f32 = flag[0]!=0;
    int i = blockIdx.x*256 + threadIdx.x;
    if (i >= PM_TOTAL) return;
    if (i < 16384){ int c=i>>5, r=i&31; dwt[i] = ldd(dcw, (size_t)r*C_+c, f32); return; }
    i -= 16384;
    if (i < 16384){ cbwf[i] = ldd(cbw, i, f32); return; }
    i -= 16384;
    if (i < 7776){
        const void* s = (i<2592)? sa1w : ((i<5184)? sa2w : sa3w);
        int j = (i<2592)? i : ((i<5184)? i-2592 : i-5184);
        saw[i] = ldd(s, j, f32); return;
    }
    i -= 7776;
    if (i < 512){ vecs[VQB +i] = ldd(q_b,  i, f32); return; } i -= 512;
    if (i < 512){ vecs[VKB +i] = ldd(k_b,  i, f32); return; } i -= 512;
    if (i < 512){ vecs[VVB +i] = ldd(v_b,  i, f32); return; } i -= 512;
    if (i < 512){ vecs[VCB +i] = ldd(c_b,  i, f32); return; } i -= 512;
    if (i < 512){ vecs[VQRY+i] = ldd(query,i, f32); return; } i -= 512;
    if (i < 96){
        const void* s = (i<32)? sa1b : ((i<64)? sa2b : sa3b);
        vecs[VSAB+i] = ldd(s, i&31, f32); return;
    }
    i -= 96;
    if (i < 6){ vecs[VW2+i] = ldd(w2, i, f32); return; } i -= 6;
    if (i < 3){ vecs[VW4+i] = ldd(w4, i, f32); return; } i -= 3;
    if (i < 3){ vecs[VWTS+i] = ldd(wts, i, f32); return; } i -= 3;
    if (i < 262144){ int r=i/C_, c=i%C_; vwt[i] = ldd(v_w, (size_t)c*C_+r, f32); return; }
    i -= 262144;
    { int r=i/C_, c=i%C_; cwt[i] = ldd(c_w, (size_t)c*C_+r, f32); }
}

// ---------- T1: x -> bf16 copy (vectorized x4; staged in first half of d_out) ----------
__global__ void __launch_bounds__(256) cvt_x_kernel(const void* __restrict__ x,
                                                    bf16* __restrict__ xb,
                                                    const int* __restrict__ flag){
    bool f32 = flag[0]!=0;
    int i4 = blockIdx.x*256 + threadIdx.x;      // index of 4-elem group
    if (i4 >= XTOT/4) return;
    ushort4v u;
    if (f32){
        float4 v = ((const float4*)x)[i4];
        u[0]=f2bu(v.x); u[1]=f2bu(v.y); u[2]=f2bu(v.z); u[3]=f2bu(v.w);
    } else {
        u = ((const ushort4v*)x)[i4];
    }
    ((ushort4v*)xb)[i4] = u;
}

// ---------- K1: fold query/q/k projections into one C-vector ----------
__global__ void qproj_kernel(const void* __restrict__ q_w, const void* __restrict__ k_w,
                             const float* __restrict__ vecs, float* __restrict__ qk_out,
                             const int* __restrict__ flag){
    bool f32 = flag[0]!=0;
    __shared__ float qp_s[C_];
    int c = threadIdx.x;                       // 512 threads
    float acc = 0.f;
    for (int i=0;i<C_;i++) acc += vecs[VQRY+i] * ldd(q_w, (size_t)c*C_+i, f32);
    qp_s[c] = (acc + vecs[VQB+c]) * 0.044194173824159216f;   // 512^-0.5
    __syncthreads();
    float a2 = 0.f;
    for (int i=0;i<C_;i++) a2 += qp_s[i] * ldd(k_w, (size_t)i*C_ + c, f32);
    qk_out[c] = a2;
    if (c==0){
        float d=0.f;
        for (int i=0;i<C_;i++) d += qp_s[i]*vecs[VKB+i];
        qk_out[C_] = d;
    }
}

// ---------- F1: attn logits + softmax + pooled / (mean,max part of xq) ----------
__global__ void __launch_bounds__(256) f1_kernel(const bf16* __restrict__ xb,
        const float* __restrict__ qk, const float* __restrict__ vecs,
        float* __restrict__ pooled, float* __restrict__ mm){
    int b = blockIdx.x, n = b/T_, t = b%T_;
    __shared__ float qk_s[C_];
    __shared__ float sm[HW_];
    __shared__ float red[2];
    int tid = threadIdx.x;
    for (int i=tid;i<C_;i+=256) qk_s[i] = qk[i];
    __syncthreads();
    if (tid < HW_){
        float acc = qk[C_];
        const bf16* p = xb + (size_t)n*SN_ + (size_t)t*HW_ + tid;
        for (int c=0;c<C_;c++) acc += qk_s[c]*b2f(p[(size_t)c*SC_]);
        sm[tid] = acc;
    }
    __syncthreads();
    if (tid==0){ float m=-1e30f; for(int l=0;l<HW_;l++) m=fmaxf(m,sm[l]); red[0]=m; }
    __syncthreads();
    if (tid < HW_) sm[tid] = __expf(sm[tid]-red[0]);
    __syncthreads();
    if (tid==0){ float s=0.f; for(int l=0;l<HW_;l++) s+=sm[l]; red[1]=1.f/s; }
    __syncthreads();
    if (tid < HW_) sm[tid] *= red[1];
    __syncthreads();
    float w40=vecs[VW4+0], w41=vecs[VW4+1];
    for (int c=tid;c<C_;c+=256){
        const bf16* base = xb + (size_t)n*SN_ + (size_t)c*SC_ + (size_t)t*HW_;
        float s=0.f, m=-1e30f, pl=0.f;
        for (int l4=0;l4<HW_;l4+=4){
            ushort4v u = *(const ushort4v*)(base + l4);
            #pragma unroll
            for (int k=0;k<4;k++){
                float v = u2f(u[k]);
                s += v; m = fmaxf(m,v); pl += sm[l4+k]*v;
            }
        }
        pooled[(size_t)b*C_+c] = pl;
        mm[(size_t)b*C_+c] = s*(1.f/HW_)*w40 + m*w41;
    }
}

// ---------- proj: v-proj -> c-proj -> xq -> yq (all coalesced) ----------
__global__ void __launch_bounds__(512) proj_kernel(const float* __restrict__ pooled,
        const float* __restrict__ mm, const float* __restrict__ vwt,
        const float* __restrict__ cwt, const void* __restrict__ dcw2,
        const float* __restrict__ vecs, float* __restrict__ xq,
        float* __restrict__ yq, const int* __restrict__ flag){
    bool f32 = flag[0]!=0;
    int b = blockIdx.x, c = threadIdx.x;       // 512 threads
    __shared__ float p_s[C_];
    __shared__ float pre_s[C_];
    __shared__ float xq_s[C_];
    p_s[c] = pooled[(size_t)b*C_ + c];
    __syncthreads();
    float pre = vecs[VVB+c];
    for (int i=0;i<C_;i++) pre += p_s[i]*vwt[(size_t)i*C_+c];
    pre_s[c] = pre;
    __syncthreads();
    float att = vecs[VCB+c];
    for (int i=0;i<C_;i++) att += pre_s[i]*cwt[(size_t)i*C_+c];
    float xqv = mm[(size_t)b*C_+c] + vecs[VW4+2]*att;
    xq[(size_t)b*C_+c] = xqv;
    xq_s[c] = xqv;
    __syncthreads();
    float yqv = 0.f;
    for (int i=0;i<C_;i++) yqv += xq_s[i]*ldd(dcw2, (size_t)i*C_+c, f32);
    yq[(size_t)b*C_+c] = yqv;
}

// ---------- corr2: gates + z + feat (rank-factorized correlation) ----------
__global__ void __launch_bounds__(256) corr2_kernel(const bf16* __restrict__ xb,
        const float* __restrict__ yq, const float* __restrict__ w2t,
        const float* __restrict__ vecs, float* __restrict__ feat){
    int b = blockIdx.x, n = b/T_, t = b%T_;
    int tid = threadIdx.x;
    __shared__ float yq_s[C_];
    __shared__ float g_s[6*HW_];
    __shared__ float z_s[C_];
    for (int i=tid;i<C_;i+=256) yq_s[i] = yq[(size_t)b*C_+i];
    __syncthreads();
    const int offs[6] = {-3,-2,-1,1,2,3};
    // ---- gate stage: thread = l ----
    if (tid < HW_){
        float accj[6] = {0.f,0.f,0.f,0.f,0.f,0.f};
        const bf16* pj[6];
        bool val[6];
        #pragma unroll
        for (int j=0;j<6;j++){
            int tj = t + offs[j];
            val[j] = (tj>=0 && tj<T_);
            pj[j] = xb + (size_t)n*SN_ + (size_t)(val[j]?tj:0)*HW_ + tid;
        }
        for (int e=0;e<C_;e++){
            size_t eo = (size_t)e*SC_;
            float yv = yq_s[e];
            #pragma unroll
            for (int j=0;j<6;j++) accj[j] += yv*b2f(pj[j][eo]);
        }
        #pragma unroll
        for (int j=0;j<6;j++){
            float w2j = vecs[VW2+j];
            g_s[j*HW_+tid] = val[j] ? w2j*(sigm(w2j*accj[j])-0.5f) : 0.f;
        }
    }
    __syncthreads();
    // ---- z stage: thread = e (2 chunks) ----
    {
        float acc0=0.f, acc1=0.f;
        const bf16* b0 = xb + (size_t)n*SN_ + (size_t)tid*SC_;
        const bf16* b1 = b0 + (size_t)256*SC_;
        #pragma unroll
        for (int j=0;j<6;j++){
            int tj = t + offs[j];
            if (tj<0 || tj>=T_) continue;
            const bf16* r0 = b0 + (size_t)tj*HW_;
            const bf16* r1 = b1 + (size_t)tj*HW_;
            const float* gp = &g_s[j*HW_];
            for (int l4=0;l4<HW_;l4+=4){
                ushort4v u0 = *(const ushort4v*)(r0+l4);
                ushort4v u1 = *(const ushort4v*)(r1+l4);
                #pragma unroll
                for (int k=0;k<4;k++){
                    float g = gp[l4+k];
                    acc0 += g*u2f(u0[k]);
                    acc1 += g*u2f(u1[k]);
                }
            }
        }
        z_s[tid]     = acc0;
        z_s[tid+256] = acc1;
    }
    __syncthreads();
    // ---- feat stage: thread = c (2 chunks), coalesced w2t ----
    for (int c=tid;c<C_;c+=256){
        float acc=0.f;
        for (int e=0;e<C_;e++) acc += w2t[(size_t)e*C_+c]*z_s[e];
        feat[(size_t)b*C_+c]=acc;
    }
}

// ---------- xdown: x_down = down_conv_w @ x (bf16 out) ----------
__global__ void __launch_bounds__(256) xdown_kernel(const bf16* __restrict__ xb,
                                                    const float* __restrict__ dwt,
                                                    bf16* __restrict__ xd){
    int b = blockIdx.x, n = b/T_, t = b%T_;
    int hw = threadIdx.x;
    int hwc = hw < HW_ ? hw : HW_-1;
    float acc[RC_];
    #pragma unroll
    for (int r=0;r<RC_;r++) acc[r]=0.f;
    const bf16* xp = xb + (size_t)n*SN_ + (size_t)t*HW_ + hwc;
    for (int c=0;c<C_;c++){
        float xv = b2f(xp[(size_t)c*SC_]);
        const float* wr = dwt + c*RC_;         // wave-uniform
        #pragma unroll
        for (int r=0;r<RC_;r++) acc[r] += wr[r]*xv;
    }
    if (hw < HW_){
        #pragma unroll
        for (int r=0;r<RC_;r++)
            xd[(((size_t)n*RC_ + r)*T_ + t)*HW_ + hw] = __float2bfloat16(acc[r]);
    }
}

// ---------- dwconv: padded-tile version, one (n,r,t) per block ----------
// tile: 9 frames, spatial pad 3 each side (20 rows), row stride 21 (bank spread)
#define TPAD 21
#define TROW 20
#define TFRM (TROW*TPAD)   // 420
__global__ void __launch_bounds__(256) dwconv_kernel(const bf16* __restrict__ xd,
        const float* __restrict__ saw, const float* __restrict__ vecs,
        float* __restrict__ aggs){
    int nr = blockIdx.x;            // n*RC_+r
    int t  = blockIdx.y;
    int r  = nr % RC_;
    __shared__ float tile[9*TFRM];
    __shared__ float wsm[3][81];
    int tid = threadIdx.x;          // 256
    for (int i=tid;i<9*TFRM;i+=256) tile[i] = 0.f;
    if (tid < 81){
        wsm[0][tid]=saw[       r*81+tid];
        wsm[1][tid]=saw[2592 + r*81+tid];
        wsm[2][tid]=saw[5184 + r*81+tid];
    }
    __syncthreads();
    const bf16* base = xd + (size_t)nr*T_*HW_;
    for (int i=tid;i<9*HW_;i+=256){
        int kt = i/HW_, hw = i - kt*HW_;
        int tg = t - 4 + kt;
        if (tg>=0 && tg<T_){
            int h = hw/W_, w = hw - h*W_;
            tile[kt*TFRM + (h+3)*TPAD + (w+3)] = b2f(base[(size_t)tg*HW_ + hw]);
        }
    }
    __syncthreads();
    if (tid < HW_){
        int h = tid/W_, w = tid - h*W_;
        float w0=vecs[VWTS+0], w1=vecs[VWTS+1], w2v=vecs[VWTS+2];
        float cbias = w0*vecs[VSAB+r] + w1*vecs[VSAB+32+r] + w2v*vecs[VSAB+64+r];
        float bacc[3];
        #pragma unroll
        for (int br=0;br<3;br++){
            int d = br+1;
            float s = 0.f;
            #pragma unroll
            for (int kt=0;kt<9;kt++){
                const float* tb = &tile[kt*TFRM + (h+3-d)*TPAD + (w+3-d)];
                const float* wp = &wsm[br][kt*9];
                s += wp[0]*tb[0]          + wp[1]*tb[d]          + wp[2]*tb[2*d]
                   + wp[3]*tb[d*TPAD]     + wp[4]*tb[d*TPAD+d]   + wp[5]*tb[d*TPAD+2*d]
                   + wp[6]*tb[2*d*TPAD]   + wp[7]*tb[2*d*TPAD+d] + wp[8]*tb[2*d*TPAD+2*d];
            }
            bacc[br] = s;
        }
        float acc = cbias + w0*bacc[0] + w1*bacc[1] + w2v*bacc[2];
        aggs[(size_t)nr*T_*HW_ + (size_t)t*HW_ + tid] = acc;
    }
}

// ---------- final: conv_back (reg-resident agg) + gate * feat -> fp32 out ----------
__global__ void __launch_bounds__(256) final_kernel(const float* __restrict__ aggs,
                                                    const float* __restrict__ cbwf,
                                                    const float* __restrict__ feat,
                                                    float* __restrict__ out){
    int b = blockIdx.x, n = b/T_, t = b%T_;
    int c0 = blockIdx.y*128;
    int hw = threadIdx.x;
    if (hw >= HW_) return;
    float ra[RC_];
    #pragma unroll
    for (int r=0;r<RC_;r++)
        ra[r] = aggs[(((size_t)n*RC_+r)*T_ + t)*HW_ + hw];
    const float* fb = feat + (size_t)b*C_;
    for (int ci=0;ci<128;ci++){
        int c = c0+ci;
        const float* wr = cbwf + c*RC_;    // wave-uniform
        float a = 0.f;
        #pragma unroll
        for (int r=0;r<RC_;r++) a += wr[r]*ra[r];
        out[(((size_t)n*C_+c)*T_ + t)*HW_ + hw] = fb[c]*(sigm(a)-0.5f);
    }
}

extern "C" void kernel_launch(void* const* d_in, const int* in_sizes, int n_in,
                              void* d_out, int out_size, void* d_ws, size_t ws_size,
                              hipStream_t stream){
    const void* x      = d_in[0];
    const void* dcw2   = d_in[1];
    const void* dcw    = d_in[2];
    const void* cbw    = d_in[3];
    const void* w2     = d_in[4];
    const void* w4     = d_in[5];
    const void* wts    = d_in[6];
    const void* query  = d_in[7];
    const void* q_w    = d_in[8];
    const void* q_b    = d_in[9];
    const void* k_w    = d_in[10];
    const void* k_b    = d_in[11];
    const void* v_w    = d_in[12];
    const void* v_b    = d_in[13];
    const void* c_w    = d_in[14];
    const void* c_b    = d_in[15];
    const void* sa1w   = d_in[16];
    const void* sa1b   = d_in[17];
    const void* sa2w   = d_in[18];
    const void* sa2b   = d_in[19];
    const void* sa3w   = d_in[20];
    const void* sa3b   = d_in[21];
    float* out = (float*)d_out;

    // workspace layout — ~12.5 MB
    float* ws    = (float*)d_ws;
    int*   flag  = (int*)ws;               // 16
    float* qk    = ws + 16;                // 1024
    float* pooled= qk + 1024;              // 98304
    float* mm    = pooled + 98304;         // 98304
    float* xq    = mm + 98304;             // 98304
    float* yq    = xq + 98304;             // 98304
    float* feat  = yq + 98304;             // 98304
    float* w2t   = feat + 98304;           // 262144
    float* vwt   = w2t + 262144;           // 262144
    float* cwt   = vwt + 262144;           // 262144
    float* dwt   = cwt + 262144;           // 16384
    float* cbwf  = dwt + 16384;            // 16384
    float* saw   = cbwf + 16384;           // 7936 (uses 7776)
    float* vecs  = saw + 7936;             // 2720
    float* aggs  = vecs + VECS_TOTAL;      // 1204224 fp32
    bf16*  xd    = (bf16*)(aggs + 1204224);// 1204224 bf16
    // xb staged in the FIRST HALF of d_out (38.5 MB of 77 MB); fully consumed
    // by f1/corr2/xdown before final_kernel overwrites all of d_out.
    bf16*  xb    = (bf16*)d_out;

    probe_kernel<<<1, 64, 0, stream>>>(x, flag);
    prep_w2t_kernel<<<(C_*C_+255)/256, 256, 0, stream>>>(dcw2, w2t, flag);
    prep_misc_kernel<<<(PM_TOTAL+255)/256, 256, 0, stream>>>(
        dcw, cbw, sa1w, sa2w, sa3w, q_b, k_b, v_b, c_b, query,
        sa1b, sa2b, sa3b, w2, w4, wts, v_w, c_w,
        dwt, cbwf, saw, vecs, vwt, cwt, flag);
    cvt_x_kernel<<<(XTOT/4+255)/256, 256, 0, stream>>>(x, xb, flag);

    qproj_kernel<<<1, C_, 0, stream>>>(q_w, k_w, vecs, qk, flag);
    f1_kernel<<<B_, 256, 0, stream>>>(xb, qk, vecs, pooled, mm);
    proj_kernel<<<B_, C_, 0, stream>>>(pooled, mm, vwt, cwt, dcw2, vecs, xq, yq, flag);
    corr2_kernel<<<B_, 256, 0, stream>>>(xb, yq, w2t, vecs, feat);

    xdown_kernel<<<B_, 256, 0, stream>>>(xb, dwt, xd);
    dwconv_kernel<<<dim3(N_*RC_, T_), 256, 0, stream>>>(xd, saw, vecs, aggs);
    final_kernel<<<dim3(B_, 4), 256, 0, stream>>>(aggs, cbwf, feat, out);
}